// Round 3
// baseline (72400.238 us; speedup 1.0000x reference)
//
#include <hip/hip_runtime.h>
#include <hip/hip_fp16.h>

#define HDIM 256
#define LSEQ 512
#define PRED 96
#define NTHR 512

__device__ __forceinline__ float sigm(float x) { return 1.f / (1.f + __expf(-x)); }
// tanh(x) = 1 - 2/(e^{2x}+1); NaN-free at +/-inf
__device__ __forceinline__ float tanh_(float x) { float t = __expf(2.f * x); return 1.f - 2.f / (t + 1.f); }

struct SmemT {
  float h[2][2][132];    // [buf][k-half][128 + pad4] fp32 hidden state
  float stg[2][2][132];  // P2 input staging (same layout)
  float xv[LSEQ];
  float wih[768];        // rank-1 input weights for scalar-input phases
  float bih[768];
  float bhh[768];
  float wo[HDIM];
  float red[8];
  float inp;
};

// Load this thread's 3 gate rows (128-wide k-slice) of a [768][256] fp32 matrix into
// packed f16 registers. Fully unrolled -> compile-time indices -> stays in VGPRs.
// 192 half2 VGPRs/thread x 512 thr = 384 KB/CU (fits the 512 KB RF; fp32 would not).
#define LOADW(PTR)                                                                 \
  {                                                                                \
    _Pragma("unroll") for (int g = 0; g < 3; ++g) {                                \
      const float2* rp = (const float2*)((PTR) + (j + (g << 8)) * HDIM + k0);      \
      _Pragma("unroll") for (int p = 0; p < 64; ++p) {                             \
        float2 f = rp[p];                                                          \
        w[g * 64 + p] = __floats2half2_rn(f.x, f.y);                               \
      }                                                                            \
    }                                                                              \
  }

// 3-gate partial dot over this thread's 128-wide k-slice, then pair-combine with the
// other k-half (lane^1, same wave). fmaf((float)h16, f32, f32) -> v_fma_mix_f32.
#define MATVEC(HP)                                                                 \
  {                                                                                \
    ar = 0.f; az = 0.f; an = 0.f;                                                  \
    const float2* hp2 = (const float2*)(HP);                                       \
    _Pragma("unroll") for (int p = 0; p < 64; ++p) {                               \
      float2 hv = hp2[p];                                                          \
      ar = fmaf(__low2float(w[p]), hv.x, ar);                                      \
      ar = fmaf(__high2float(w[p]), hv.y, ar);                                     \
      az = fmaf(__low2float(w[64 + p]), hv.x, az);                                 \
      az = fmaf(__high2float(w[64 + p]), hv.y, az);                                \
      an = fmaf(__low2float(w[128 + p]), hv.x, an);                                \
      an = fmaf(__high2float(w[128 + p]), hv.y, an);                               \
    }                                                                              \
    ar += __shfl_xor(ar, 1); az += __shfl_xor(az, 1); an += __shfl_xor(an, 1);     \
  }

__global__ __launch_bounds__(NTHR, 2) void gru_forecast(
    const float* __restrict__ x,
    const float* __restrict__ Wih0, const float* __restrict__ Whh0,
    const float* __restrict__ bih0, const float* __restrict__ bhh0,
    const float* __restrict__ Wih1, const float* __restrict__ Whh1,
    const float* __restrict__ bih1, const float* __restrict__ bhh1,
    const float* __restrict__ Wdih, const float* __restrict__ Wdhh,
    const float* __restrict__ bdih, const float* __restrict__ bdhh,
    const float* __restrict__ Wo, const float* __restrict__ bo,
    float* __restrict__ out, __half* __restrict__ ys, __half* __restrict__ gi) {
  __shared__ SmemT s;
  const int tid = threadIdx.x;
  const int b = blockIdx.x;
  const int j = tid >> 1;      // output/gate row within H
  const int half = tid & 1;    // k-slice half
  const int k0 = half << 7;
  __half2 w[192];              // 3 gates x 64 half2 = this thread's weight slice
  float ar, az, an;

  // ---------------- Phase 1: encoder GRU layer 0 (input_size=1) ----------------
  s.xv[tid] = x[(size_t)b * LSEQ + tid];
  // NOTE: NTHR=512 < 768 -> strided loop, NOT `if (tid<768)` (Round-0/1 NaN bug)
  for (int i = tid; i < 768; i += NTHR) {
    s.wih[i] = Wih0[i]; s.bih[i] = bih0[i]; s.bhh[i] = bhh0[i];
  }
  if (tid < 264) ((float*)s.h[0])[tid] = 0.f;
  LOADW(Whh0);
  __syncthreads();

  int pb = 0;
  for (int t = 0; t < LSEQ; ++t) {
    MATVEC(s.h[pb][half]);
    const float xt = s.xv[t];
    const float ghr = ar + s.bhh[j], ghz = az + s.bhh[j + 256], ghn = an + s.bhh[j + 512];
    const float r = sigm(fmaf(xt, s.wih[j], s.bih[j]) + ghr);
    const float z = sigm(fmaf(xt, s.wih[j + 256], s.bih[j + 256]) + ghz);
    const float n = tanh_(fmaf(r, ghn, fmaf(xt, s.wih[j + 512], s.bih[j + 512])));
    const float hold = s.h[pb][j >> 7][j & 127];
    const float hn = fmaf(z, hold - n, n);
    if (!half) {
      s.h[pb ^ 1][j >> 7][j & 127] = hn;
      ys[((size_t)b * LSEQ + t) * HDIM + j] = __float2half(hn);  // |h| < 1: f16-safe
    }
    pb ^= 1;
    __syncthreads();
  }

  // -------- Phase 2: GI1[t] = ys0[t] @ W_ih1.T + b_ih1 (no recurrence) --------
  LOADW(Wih1);
  for (int i = tid; i < 768; i += NTHR) s.bih[i] = bih1[i];
  if (tid < 128) {
    __half2 v = ((const __half2*)(ys + (size_t)b * LSEQ * HDIM))[tid];
    float2 f = __half22float2(v);
    s.stg[0][tid >> 6][(tid & 63) << 1] = f.x;
    s.stg[0][tid >> 6][((tid & 63) << 1) + 1] = f.y;
  }
  __syncthreads();
  for (int t = 0; t < LSEQ; ++t) {
    float2 nf;
    const bool ld = (t + 1 < LSEQ) && (tid < 128);
    if (ld) {
      __half2 v = ((const __half2*)(ys + ((size_t)b * LSEQ + t + 1) * HDIM))[tid];
      nf = __half22float2(v);
    }
    MATVEC(s.stg[t & 1][half]);
    if (!half) {
      const size_t o = ((size_t)b * LSEQ + t) * 768;
      gi[o + j] = __float2half(ar + s.bih[j]);
      gi[o + j + 256] = __float2half(az + s.bih[j + 256]);
      gi[o + j + 512] = __float2half(an + s.bih[j + 512]);
    }
    if (ld) {
      s.stg[(t + 1) & 1][tid >> 6][(tid & 63) << 1] = nf.x;
      s.stg[(t + 1) & 1][tid >> 6][((tid & 63) << 1) + 1] = nf.y;
    }
    __syncthreads();
  }

  // ---------------- Phase 3: encoder GRU layer 1 (uses precomputed GI) --------
  LOADW(Whh1);
  for (int i = tid; i < 768; i += NTHR) s.bhh[i] = bhh1[i];
  if (tid < 264) ((float*)s.h[0])[tid] = 0.f;
  __syncthreads();
  pb = 0;
  for (int t = 0; t < LSEQ; ++t) {
    const size_t o = ((size_t)b * LSEQ + t) * 768;
    const float gr = __half2float(gi[o + j]);           // prefetch before matvec;
    const float gz = __half2float(gi[o + j + 256]);     // latency hidden under fma_mix
    const float gn = __half2float(gi[o + j + 512]);
    MATVEC(s.h[pb][half]);
    const float ghr = ar + s.bhh[j], ghz = az + s.bhh[j + 256], ghn = an + s.bhh[j + 512];
    const float r = sigm(gr + ghr);
    const float z = sigm(gz + ghz);
    const float n = tanh_(fmaf(r, ghn, gn));
    const float hold = s.h[pb][j >> 7][j & 127];
    const float hn = fmaf(z, hold - n, n);
    if (!half) s.h[pb ^ 1][j >> 7][j & 127] = hn;
    pb ^= 1;
    __syncthreads();
  }

  // ---------------- Phase 4: autoregressive decoder (96 steps) ----------------
  LOADW(Wdhh);
  for (int i = tid; i < 768; i += NTHR) {
    s.wih[i] = Wdih[i]; s.bih[i] = bdih[i]; s.bhh[i] = bdhh[i];
  }
  if (tid < HDIM) s.wo[tid] = Wo[tid];
  if (tid == 0) s.inp = 0.f;
  const float bov = bo[0];
  __syncthreads();
  for (int t = 0; t < PRED; ++t) {
    const float it = s.inp;
    MATVEC(s.h[pb][half]);
    const float ghr = ar + s.bhh[j], ghz = az + s.bhh[j + 256], ghn = an + s.bhh[j + 512];
    const float r = sigm(fmaf(it, s.wih[j], s.bih[j]) + ghr);
    const float z = sigm(fmaf(it, s.wih[j + 256], s.bih[j + 256]) + ghz);
    const float n = tanh_(fmaf(r, ghn, fmaf(it, s.wih[j + 512], s.bih[j + 512])));
    const float hold = s.h[pb][j >> 7][j & 127];
    const float hn = fmaf(z, hold - n, n);
    float c = half ? 0.f : s.wo[j] * hn;
#pragma unroll
    for (int off = 1; off < 64; off <<= 1) c += __shfl_xor(c, off);
    if (!half) s.h[pb ^ 1][j >> 7][j & 127] = hn;
    if ((tid & 63) == 0) s.red[tid >> 6] = c;
    pb ^= 1;
    __syncthreads();
    if (tid == 0) {
      float ov = s.red[0] + s.red[1] + s.red[2] + s.red[3] +
                 s.red[4] + s.red[5] + s.red[6] + s.red[7] + bov;
      out[(size_t)b * PRED + t] = ov;
      s.inp = ov;
    }
    __syncthreads();
  }
}

extern "C" void kernel_launch(void* const* d_in, const int* in_sizes, int n_in,
                              void* d_out, int out_size, void* d_ws, size_t ws_size,
                              hipStream_t stream) {
  const float* x    = (const float*)d_in[0];
  const float* Wih0 = (const float*)d_in[1];
  const float* Whh0 = (const float*)d_in[2];
  const float* bih0 = (const float*)d_in[3];
  const float* bhh0 = (const float*)d_in[4];
  const float* Wih1 = (const float*)d_in[5];
  const float* Whh1 = (const float*)d_in[6];
  const float* bih1 = (const float*)d_in[7];
  const float* bhh1 = (const float*)d_in[8];
  const float* Wdih = (const float*)d_in[9];
  const float* Wdhh = (const float*)d_in[10];
  const float* bdih = (const float*)d_in[11];
  const float* bdhh = (const float*)d_in[12];
  const float* Wo   = (const float*)d_in[13];
  const float* bo   = (const float*)d_in[14];

  // ws layout: ys0 (f16, 256*512*256 = 64 MiB) | GI1 (f16, 256*512*768 = 192 MiB)
  __half* ys = (__half*)d_ws;
  __half* gi = ys + (size_t)256 * 512 * 256;

  gru_forecast<<<256, NTHR, 0, stream>>>(x, Wih0, Whh0, bih0, bhh0,
                                         Wih1, Whh1, bih1, bhh1,
                                         Wdih, Wdhh, bdih, bdhh, Wo, bo,
                                         (float*)d_out, ys, gi);
}